// Round 1
// baseline (96.191 us; speedup 1.0000x reference)
//
#include <hip/hip_runtime.h>

#define L2E 1.4426950408889634f
#define MAXL 1024

__device__ __forceinline__ float fexp2(float x) {
#if __has_builtin(__builtin_amdgcn_exp2f)
  return __builtin_amdgcn_exp2f(x);
#else
  float r; asm("v_exp_f32 %0, %1" : "=v"(r) : "v"(x)); return r;
#endif
}

__device__ __forceinline__ float frcp(float x) {
  return __builtin_amdgcn_rcpf(x);
}

template<int CTRL>
__device__ __forceinline__ float quad_bcast(float x) {
  // quad_perm DPP: every lane of each physical quad reads quad-lane (CTRL pattern)
  return __int_as_float(__builtin_amdgcn_mov_dpp(__float_as_int(x), CTRL, 0xF, 0xF, true));
}

__device__ __forceinline__ float readlanef(float x, int lane) {
  return __int_as_float(__builtin_amdgcn_readlane(__float_as_int(x), lane));
}

// Lane layout (m = lane % 12): channel k = m>>2, gate type = m&3 (0=i,1=f,2=g,3=o).
// Reference gate row r = (m&3)*3 + (m>>2).  i/f/g/o of one channel share a quad.
__global__ __launch_bounds__(256) void lstm_scan_softmax(
    const float* __restrict__ state,
    const float* __restrict__ W_ih,   // (5,12,1)
    const float* __restrict__ W_hh,   // (5,12,3)
    const float* __restrict__ b_ih,   // (5,12)
    const float* __restrict__ b_hh,   // (5,12)
    float* __restrict__ out, int L)
{
  __shared__ float wib[60];            // W_ih[u][r]
  __shared__ float bsum[60];           // b_ih + b_hh
  __shared__ float whl[180];           // W_hh (for tail path)
  __shared__ float pre_lds[MAXL * 12]; // wi*x + b  per (t, m)
  __shared__ float hs_lds[MAXL * 3];   // h history

  const int tid = threadIdx.x;

  // ---- stage small weights ----
  if (tid < 60)  { wib[tid] = W_ih[tid]; bsum[tid] = b_ih[tid] + b_hh[tid]; }
  if (tid < 180) { whl[tid] = W_hh[tid]; }
  __syncthreads();

  // ---- parallel precompute: pre[t][m] = wi[r]*x[t] + b[r]  (h-independent) ----
  for (int t = tid; t < L; t += 256) {
    float x = state[t];
    int u = t % 5;
    #pragma unroll
    for (int m = 0; m < 12; ++m) {
      int r = (m & 3) * 3 + (m >> 2);
      pre_lds[t * 12 + m] = fmaf(wib[u * 12 + r], x, bsum[u * 12 + r]);
    }
  }
  __syncthreads();

  // ---- sequential scan: wave 0 only, all 64 lanes replicate lanes 0..11 ----
  if (tid < 64) {
    const int m = tid % 12;
    const int r = (m & 3) * 3 + (m >> 2);
    const bool is_g = (m & 3) == 2;
    // activation = A * rcp(1 + exp2(sc * x)) + B   (sigmoid or tanh, branchless)
    const float sc = is_g ? (2.0f * L2E) : (-L2E);
    const float Aa = is_g ? -2.0f : 1.0f;
    const float Bb = is_g ? 1.0f : 0.0f;

    // W_hh rows for this lane's gate, all 5 unique layers, in registers
    float wh[5][3];
    #pragma unroll
    for (int u = 0; u < 5; ++u)
      #pragma unroll
      for (int j = 0; j < 3; ++j)
        wh[u][j] = W_hh[u * 36 + r * 3 + j];

    const bool writer = (tid < 12) && ((tid & 3) == 0); // lanes 0,4,8
    const int  kidx = tid >> 2;

    float h0 = 0.f, h1 = 0.f, h2 = 0.f, c = 0.f;

    const int L5 = (L / 5) * 5;
    for (int t5 = 0; t5 < L5; t5 += 5) {
      // prefetch 5 steps of pre (independent of the h/c chain)
      float p[5];
      #pragma unroll
      for (int u = 0; u < 5; ++u) p[u] = pre_lds[(t5 + u) * 12 + m];
      #pragma unroll
      for (int u = 0; u < 5; ++u) {
        float g = fmaf(wh[u][0], h0, p[u]);
        g = fmaf(wh[u][1], h1, g);
        g = fmaf(wh[u][2], h2, g);
        float a  = fmaf(Aa, frcp(1.0f + fexp2(sc * g)), Bb);
        float iv = quad_bcast<0x00>(a);
        float fv = quad_bcast<0x55>(a);
        float gv = quad_bcast<0xAA>(a);
        float ov = quad_bcast<0xFF>(a);
        c = fmaf(fv, c, iv * gv);
        float tc = fmaf(-2.0f, frcp(1.0f + fexp2(2.0f * L2E * c)), 1.0f);
        float h  = ov * tc;
        h0 = readlanef(h, 0);
        h1 = readlanef(h, 4);
        h2 = readlanef(h, 8);
        if (writer) hs_lds[(t5 + u) * 3 + kidx] = h;
      }
    }
    // tail (L % 5 != 0) — W_hh from LDS
    for (int t = L5; t < L; ++t) {
      int u = t % 5;
      float w0 = whl[u * 36 + r * 3 + 0];
      float w1 = whl[u * 36 + r * 3 + 1];
      float w2 = whl[u * 36 + r * 3 + 2];
      float g = fmaf(w0, h0, pre_lds[t * 12 + m]);
      g = fmaf(w1, h1, g);
      g = fmaf(w2, h2, g);
      float a  = fmaf(Aa, frcp(1.0f + fexp2(sc * g)), Bb);
      float iv = quad_bcast<0x00>(a);
      float fv = quad_bcast<0x55>(a);
      float gv = quad_bcast<0xAA>(a);
      float ov = quad_bcast<0xFF>(a);
      c = fmaf(fv, c, iv * gv);
      float tc = fmaf(-2.0f, frcp(1.0f + fexp2(2.0f * L2E * c)), 1.0f);
      float h  = ov * tc;
      h0 = readlanef(h, 0);
      h1 = readlanef(h, 4);
      h2 = readlanef(h, 8);
      if (writer) hs_lds[t * 3 + kidx] = h;
    }
  }
  __syncthreads();

  // ---- parallel epilogue: softmax over axis -1 (|h| <= 1, no max-subtract needed) ----
  for (int t = tid; t < L; t += 256) {
    float a0 = hs_lds[t * 3 + 0];
    float a1 = hs_lds[t * 3 + 1];
    float a2 = hs_lds[t * 3 + 2];
    float e0 = fexp2(a0 * L2E);
    float e1 = fexp2(a1 * L2E);
    float e2 = fexp2(a2 * L2E);
    float rs = frcp(e0 + e1 + e2);
    out[t * 3 + 0] = e0 * rs;
    out[t * 3 + 1] = e1 * rs;
    out[t * 3 + 2] = e2 * rs;
  }
}

extern "C" void kernel_launch(void* const* d_in, const int* in_sizes, int n_in,
                              void* d_out, int out_size, void* d_ws, size_t ws_size,
                              hipStream_t stream) {
  const float* state = (const float*)d_in[0];
  const float* W_ih  = (const float*)d_in[1];
  const float* W_hh  = (const float*)d_in[2];
  const float* b_ih  = (const float*)d_in[3];
  const float* b_hh  = (const float*)d_in[4];
  float* out = (float*)d_out;
  int L = in_sizes[0];
  lstm_scan_softmax<<<1, 256, 0, stream>>>(state, W_ih, W_hh, b_ih, b_hh, out, L);
}